// Round 1
// baseline (4330.430 us; speedup 1.0000x reference)
//
#include <hip/hip_runtime.h>

typedef _Float16 h8 __attribute__((ext_vector_type(8)));
typedef float f4 __attribute__((ext_vector_type(4)));

namespace {

constexpr int DM   = 768;
constexpr int NHEAD= 8;
constexpr int DQ   = 96;
constexpr int DFF  = 3072;
constexpr int NL   = 6;
constexpr int B_   = 64;
constexpr int T0   = 396, T1 = 198, T2 = 99;
constexpr int FIN  = 128;
constexpr int L_   = 100;
constexpr int MSEQ = B_ * L_;    // 6400
constexpr int M1   = B_ * T1;    // 12672
constexpr int M2   = B_ * T2;    // 6336
constexpr int NREL = 201;
constexpr int POSN = 256;        // padded 199 -> 256

enum { EPI_F32 = 0, EPI_RELU_H, EPI_H, EPI_CONV_F32, EPI_CONV_RELU_H, EPI_CONV_ADD_RELU_H };

// ---------------------------------------------------------------------------
// Generic MFMA GEMM:  C[M,N] = A[M,K] @ B[N,K]^T   (B stored row-major (N,K))
// A: f16 row-major with row stride lda. Tile 64x64, BK=32, 4 waves (each 32x32
// = 2x2 MFMA frags of v_mfma_f32_16x16x32_f16, fp32 accum).
// CONV mode: A-row m -> (b = m/T_out, t = m%T_out), input row tin = t*stride+dk-pad
// with zero padding; K-loop repeated for dk in [0,KS); B advances by N*K per dk.
// blockIdx.z batching via a_z / b_z / c_z element offsets (used for pos-GEMM).
// ---------------------------------------------------------------------------
template<bool CONV, int EPI>
__global__ __launch_bounds__(256)
void gemm_k(const _Float16* __restrict__ A, const _Float16* __restrict__ B,
            float* __restrict__ Cf, _Float16* __restrict__ Ch,
            const float* __restrict__ bias, const float* __restrict__ bns,
            const float* __restrict__ bnb, const float* __restrict__ res,
            int M, int N, int K, int lda,
            int T_out, int T_in, int stride_t, int KS,
            size_t a_z, size_t b_z, size_t c_z)
{
    __shared__ _Float16 As[64][40];   // pitch 40 halves (80B) -> conflict-light
    __shared__ _Float16 Bs[64][40];

    A += (size_t)blockIdx.z * a_z;
    B += (size_t)blockIdx.z * b_z;

    const int tid  = threadIdx.x;
    const int lane = tid & 63;
    const int wid  = tid >> 6;
    const int m0   = blockIdx.y * 64;
    const int n0   = blockIdx.x * 64;
    const int wm   = (wid >> 1) * 32;
    const int wn   = (wid & 1) * 32;

    f4 acc[2][2];
    #pragma unroll
    for (int i = 0; i < 2; ++i)
        #pragma unroll
        for (int j = 0; j < 2; ++j)
            #pragma unroll
            for (int q = 0; q < 4; ++q) acc[i][j][q] = 0.0f;

    const int srow = tid >> 2;        // 0..63 staging row
    const int skq  = (tid & 3) * 8;   // 0,8,16,24

    const bool mrow_ok = (m0 + srow) < M;
    int ab = 0, at = 0;
    if (CONV) { int m = m0 + srow; ab = m / T_out; at = m - ab * T_out; }

    const int nks = CONV ? KS : 1;
    const int pad = CONV ? ((KS - 1) >> 1) : 0;

    for (int dk = 0; dk < nks; ++dk) {
        const _Float16* Bd = B + (size_t)dk * ((size_t)N * (size_t)K);
        const _Float16* Arow = nullptr;
        bool aok;
        if (CONV) {
            int tin = at * stride_t + dk - pad;
            aok = mrow_ok && tin >= 0 && tin < T_in;
            if (aok) Arow = A + ((size_t)ab * T_in + tin) * (size_t)lda;
        } else {
            aok = mrow_ok;
            if (aok) Arow = A + (size_t)(m0 + srow) * (size_t)lda;
        }
        const _Float16* Brow = Bd + (size_t)(n0 + srow) * (size_t)K;

        for (int k0 = 0; k0 < K; k0 += 32) {
            h8 av;
            #pragma unroll
            for (int q = 0; q < 8; ++q) av[q] = (_Float16)0.0f;
            if (aok) av = *(const h8*)(Arow + k0 + skq);
            h8 bv = *(const h8*)(Brow + k0 + skq);   // N multiple of 64 (buffers padded)
            *(h8*)&As[srow][skq] = av;
            *(h8*)&Bs[srow][skq] = bv;
            __syncthreads();

            const int fr = lane & 15;
            const int fk = (lane >> 4) * 8;
            h8 a0 = *(const h8*)&As[wm + fr][fk];
            h8 a1 = *(const h8*)&As[wm + 16 + fr][fk];
            h8 b0 = *(const h8*)&Bs[wn + fr][fk];
            h8 b1 = *(const h8*)&Bs[wn + 16 + fr][fk];
            acc[0][0] = __builtin_amdgcn_mfma_f32_16x16x32_f16(a0, b0, acc[0][0], 0, 0, 0);
            acc[0][1] = __builtin_amdgcn_mfma_f32_16x16x32_f16(a0, b1, acc[0][1], 0, 0, 0);
            acc[1][0] = __builtin_amdgcn_mfma_f32_16x16x32_f16(a1, b0, acc[1][0], 0, 0, 0);
            acc[1][1] = __builtin_amdgcn_mfma_f32_16x16x32_f16(a1, b1, acc[1][1], 0, 0, 0);
            __syncthreads();
        }
    }

    // Epilogue. Verified C/D mapping: col = lane&15, row = (lane>>4)*4 + reg.
    const int fr  = lane & 15;
    const int fq4 = (lane >> 4) * 4;
    float*     Cfo = Cf ? Cf + (size_t)blockIdx.z * c_z : nullptr;
    _Float16*  Cho = Ch ? Ch + (size_t)blockIdx.z * c_z : nullptr;
    #pragma unroll
    for (int mi = 0; mi < 2; ++mi)
        #pragma unroll
        for (int ni = 0; ni < 2; ++ni)
            #pragma unroll
            for (int r = 0; r < 4; ++r) {
                int row = m0 + wm + mi * 16 + fq4 + r;
                int col = n0 + wn + ni * 16 + fr;
                if (row >= M) continue;
                float v = acc[mi][ni][r];
                size_t off = (size_t)row * N + col;
                if (EPI == EPI_F32) {
                    if (bias) v += bias[col];
                    Cfo[off] = v;
                } else if (EPI == EPI_RELU_H) {
                    if (bias) v += bias[col];
                    Cho[off] = (_Float16)fmaxf(v, 0.0f);
                } else if (EPI == EPI_H) {
                    Cho[off] = (_Float16)v;
                } else if (EPI == EPI_CONV_F32) {
                    v = bns[col] * (v + bias[col]) + bnb[col];
                    Cfo[off] = v;
                } else if (EPI == EPI_CONV_RELU_H) {
                    v = bns[col] * (v + bias[col]) + bnb[col];
                    Cho[off] = (_Float16)fmaxf(v, 0.0f);
                } else { // EPI_CONV_ADD_RELU_H
                    v = bns[col] * (v + bias[col]) + bnb[col] + res[off];
                    Cho[off] = (_Float16)fmaxf(v, 0.0f);
                }
            }
}

// ------------------------- small helper kernels ----------------------------

__global__ void f2h_k(const float* __restrict__ in, _Float16* __restrict__ out,
                      long n, float scale)
{
    long i = (long)blockIdx.x * blockDim.x + threadIdx.x;
    if (i < n) out[i] = (_Float16)(in[i] * scale);
}

// wq/wk/wv (L,H,DM,DQ) f32 -> qkvw (L, 3*DM=2304, DM) f16, n = s*768+h*96+a, k = f
__global__ void pack_qkv_k(const float* __restrict__ wq, const float* __restrict__ wk,
                           const float* __restrict__ wv, _Float16* __restrict__ out)
{
    long i = (long)blockIdx.x * blockDim.x + threadIdx.x;
    if (i >= (long)NL * 2304 * DM) return;
    int  f = (int)(i % DM);
    long r = i / DM;
    int  n = (int)(r % 2304);
    int  l = (int)(r / 2304);
    int  s = n / DM, hn = n % DM, h = hn / DQ, a = hn % DQ;
    const float* src = (s == 0) ? wq : ((s == 1) ? wk : wv);
    out[i] = (_Float16)src[(((long)l * NHEAD + h) * DM + f) * DQ + a];
}

// wo (L,H,DQ,DM) f32 -> wow (L, DM, DM) f16 with n = f(out feature), k = h*96+a
__global__ void pack_wo_k(const float* __restrict__ wo, _Float16* __restrict__ out)
{
    long i = (long)blockIdx.x * blockDim.x + threadIdx.x;
    if (i >= (long)NL * DM * DM) return;
    int  ha = (int)(i % DM);
    long r  = i / DM;
    int  f  = (int)(r % DM);
    int  l  = (int)(r / DM);
    int  h = ha / DQ, a = ha % DQ;
    out[i] = (_Float16)wo[(((long)l * NHEAD + h) * DQ + a) * DM + f];
}

// conv weight (Cout, Cin, KS) f32 -> (KS, Cout, Cin) f16
__global__ void pack_conv_k(const float* __restrict__ w, _Float16* __restrict__ out,
                            int Cout, int Cin, int KS)
{
    long i = (long)blockIdx.x * blockDim.x + threadIdx.x;
    if (i >= (long)Cout * Cin * KS) return;
    int  ci = (int)(i % Cin);
    long r  = i / Cin;
    int  co = (int)(r % Cout);
    int  dk = (int)(r / Cout);
    out[i] = (_Float16)w[((long)co * Cin + ci) * KS + dk];
}

// build x_seq (B,100,768): row 0 = cls token, rows 1..99 from x_lin (B,99,768)
__global__ void concat_k(const float* __restrict__ xlin, const float* __restrict__ cls,
                         float* __restrict__ xf, _Float16* __restrict__ xh)
{
    long i = (long)blockIdx.x * blockDim.x + threadIdx.x;
    if (i >= (long)MSEQ * DM) return;
    int  c = (int)(i % DM);
    long m = i / DM;
    int  b = (int)(m / L_), t = (int)(m % L_);
    float v = (t == 0) ? cls[c] : xlin[((long)b * (L_ - 1) + (t - 1)) * DM + c];
    xf[i] = v;
    xh[i] = (_Float16)v;
}

// fused residual + LayerNorm, writes fp32 + f16 copies. In-place safe on x/xo.
__global__ __launch_bounds__(256)
void ln_k(const float* x, const float* __restrict__ d,
          const float* __restrict__ g, const float* __restrict__ bb,
          float* xo, _Float16* __restrict__ xh)
{
    long row = blockIdx.x;
    const float* xr = x + row * DM;
    const float* dr = d + row * DM;
    float v[3];
    float s = 0.0f;
    #pragma unroll
    for (int k = 0; k < 3; ++k) {
        int c = threadIdx.x + 256 * k;
        v[k] = xr[c] + dr[c];
        s += v[k];
    }
    __shared__ float red[8];
    #pragma unroll
    for (int o = 32; o; o >>= 1) s += __shfl_xor(s, o, 64);
    int w = threadIdx.x >> 6, lane = threadIdx.x & 63;
    if (lane == 0) red[w] = s;
    __syncthreads();
    s = red[0] + red[1] + red[2] + red[3];
    float mean = s * (1.0f / DM);
    float vs = 0.0f;
    #pragma unroll
    for (int k = 0; k < 3; ++k) { float t = v[k] - mean; vs += t * t; }
    #pragma unroll
    for (int o = 32; o; o >>= 1) vs += __shfl_xor(vs, o, 64);
    if (lane == 0) red[4 + w] = vs;
    __syncthreads();
    vs = red[4] + red[5] + red[6] + red[7];
    float rstd = rsqrtf(vs * (1.0f / DM) + 1e-5f);
    #pragma unroll
    for (int k = 0; k < 3; ++k) {
        int c = threadIdx.x + 256 * k;
        float y = (v[k] - mean) * rstd * g[c] + bb[c];
        xo[row * DM + c] = y;
        xh[row * DM + c] = (_Float16)y;
    }
}

// fused attention per (head h = blockIdx.x, batch b = blockIdx.y).
// qkv: (6400, 2304) f16 [q|k|v each 768 = h*96+a]. pos: (H, 6400, 256) f16.
// K staged fp32 (pre-scaled by 96^-0.5), V staged f16. 62.3KB LDS -> 2 blk/CU.
__global__ __launch_bounds__(256)
void attn_k(const _Float16* __restrict__ qkv, const _Float16* __restrict__ pos,
            _Float16* __restrict__ o)
{
    const int h = blockIdx.x, b = blockIdx.y;
    __shared__ float    Ks[L_ * 100];     // pitch 100 (16B-aligned f4 rows)
    __shared__ _Float16 Vsh[L_ * DQ];
    __shared__ float    qs[4][DQ];
    __shared__ float    ps[4][L_];
    const int tid = threadIdx.x, lane = tid & 63, w = tid >> 6;
    const _Float16* base = qkv + (size_t)b * L_ * 2304 + h * DQ;
    const float qscale = 0.10206207261596575f;  // 96^-0.5

    for (int idx = tid; idx < L_ * DQ; idx += 256) {
        int j = idx / DQ, a = idx - j * DQ;
        Ks[j * 100 + a] = (float)base[768 + (size_t)j * 2304 + a] * qscale;
        Vsh[j * DQ + a] = base[1536 + (size_t)j * 2304 + a];
    }
    __syncthreads();

    const _Float16* posb = pos + ((size_t)h * MSEQ + (size_t)b * L_) * POSN;

    for (int i = w; i < L_; i += 4) {
        for (int a = lane; a < DQ; a += 64)
            qs[w][a] = (float)base[(size_t)i * 2304 + a];

        int  j0 = lane;
        int  j1 = lane + 64;
        bool has1 = j1 < L_;
        int  j1c = has1 ? j1 : j0;
        float s0 = 0.0f, s1 = 0.0f;
        #pragma unroll
        for (int a = 0; a < DQ; a += 4) {
            f4 qa = *(const f4*)&qs[w][a];
            f4 k0 = *(const f4*)&Ks[j0 * 100 + a];
            f4 k1 = *(const f4*)&Ks[j1c * 100 + a];
            s0 += qa[0]*k0[0] + qa[1]*k0[1] + qa[2]*k0[2] + qa[3]*k0[3];
            s1 += qa[0]*k1[0] + qa[1]*k1[1] + qa[2]*k1[2] + qa[3]*k1[3];
        }
        s0 += (float)posb[(size_t)i * POSN + (j0 - i + L_ - 1)];
        if (has1) s1 += (float)posb[(size_t)i * POSN + (j1 - i + L_ - 1)];

        float mx = fmaxf(s0, has1 ? s1 : -3.0e38f);
        #pragma unroll
        for (int o2 = 32; o2; o2 >>= 1) mx = fmaxf(mx, __shfl_xor(mx, o2, 64));
        float e0 = __expf(s0 - mx);
        float e1 = has1 ? __expf(s1 - mx) : 0.0f;
        float sm = e0 + e1;
        #pragma unroll
        for (int o2 = 32; o2; o2 >>= 1) sm += __shfl_xor(sm, o2, 64);
        float inv = 1.0f / sm;
        ps[w][j0] = e0 * inv;
        if (has1) ps[w][j1] = e1 * inv;

        float acc0 = 0.0f, acc1 = 0.0f;
        for (int j = 0; j < L_; ++j) {
            float pj = ps[w][j];
            acc0 += pj * (float)Vsh[j * DQ + lane];
            if (lane < 32) acc1 += pj * (float)Vsh[j * DQ + 64 + lane];
        }
        _Float16* ob = o + ((size_t)(b * L_ + i) * DM + h * DQ);
        ob[lane] = (_Float16)acc0;
        if (lane < 32) ob[64 + lane] = (_Float16)acc1;
    }
}

// final: out[b, n] = x_seq[b, 0, :] . w_out[n, :] + bias[n]   (fp32 throughout)
__global__ __launch_bounds__(256)
void out_k(const float* __restrict__ xseq, const float* __restrict__ w,
           const float* __restrict__ bias, float* __restrict__ out)
{
    __shared__ float xs[DM];
    int b = blockIdx.x;
    for (int c = threadIdx.x; c < DM; c += 256) xs[c] = xseq[(size_t)b * L_ * DM + c];
    __syncthreads();
    int n = threadIdx.x;   // 256 outputs
    const f4* wr = (const f4*)(w + (size_t)n * DM);
    float acc = 0.0f;
    #pragma unroll 4
    for (int k4 = 0; k4 < DM / 4; ++k4) {
        f4 wv = wr[k4];
        f4 xv = *(const f4*)&xs[k4 * 4];
        acc += wv[0]*xv[0] + wv[1]*xv[1] + wv[2]*xv[2] + wv[3]*xv[3];
    }
    out[(size_t)b * 256 + n] = acc + bias[n];
}

} // anonymous namespace

// ---------------------------------------------------------------------------
extern "C" void kernel_launch(void* const* d_in, const int* in_sizes, int n_in,
                              void* d_out, int out_size, void* d_ws, size_t ws_size,
                              hipStream_t stream)
{
    (void)in_sizes; (void)n_in; (void)out_size; (void)ws_size;

    const float* x_raw   = (const float*)d_in[0];
    const float* rb1_c1w = (const float*)d_in[1];
    const float* rb1_c1b = (const float*)d_in[2];
    const float* rb1_s1  = (const float*)d_in[3];
    const float* rb1_b1  = (const float*)d_in[4];
    const float* rb1_c2w = (const float*)d_in[5];
    const float* rb1_c2b = (const float*)d_in[6];
    const float* rb1_s2  = (const float*)d_in[7];
    const float* rb1_b2  = (const float*)d_in[8];
    const float* rb1_crw = (const float*)d_in[9];
    const float* rb1_crb = (const float*)d_in[10];
    const float* rb1_sr  = (const float*)d_in[11];
    const float* rb1_br  = (const float*)d_in[12];
    const float* rb2_c1w = (const float*)d_in[13];
    const float* rb2_c1b = (const float*)d_in[14];
    const float* rb2_s1  = (const float*)d_in[15];
    const float* rb2_b1  = (const float*)d_in[16];
    const float* rb2_c2w = (const float*)d_in[17];
    const float* rb2_c2b = (const float*)d_in[18];
    const float* rb2_s2  = (const float*)d_in[19];
    const float* rb2_b2  = (const float*)d_in[20];
    const float* rb2_crw = (const float*)d_in[21];
    const float* rb2_crb = (const float*)d_in[22];
    const float* rb2_sr  = (const float*)d_in[23];
    const float* rb2_br  = (const float*)d_in[24];
    const float* w_in_w  = (const float*)d_in[25];
    const float* w_in_b  = (const float*)d_in[26];
    const float* cls     = (const float*)d_in[27];
    const float* wq      = (const float*)d_in[28];
    const float* wk      = (const float*)d_in[29];
    const float* wv      = (const float*)d_in[30];
    const float* wo      = (const float*)d_in[31];
    const float* rel     = (const float*)d_in[32];
    const float* ln1g    = (const float*)d_in[33];
    const float* ln1b    = (const float*)d_in[34];
    const float* ln2g    = (const float*)d_in[35];
    const float* ln2b    = (const float*)d_in[36];
    const float* ff1w    = (const float*)d_in[37];
    const float* ff1b    = (const float*)d_in[38];
    const float* ff2w    = (const float*)d_in[39];
    const float* ff2b    = (const float*)d_in[40];
    const float* w_out_w = (const float*)d_in[41];
    const float* w_out_b = (const float*)d_in[42];

    // ---- workspace carving (~243 MB) ----
    char* base = (char*)d_ws;
    size_t off = 0;
    auto carve = [&](size_t bytes) -> char* {
        char* p = base + off;
        off = (off + bytes + 255) & ~(size_t)255;
        return p;
    };
    _Float16* w_in_h = (_Float16*)carve((size_t)589824 * 2);
    _Float16* qkvw   = (_Float16*)carve((size_t)10616832 * 2);
    _Float16* wow    = (_Float16*)carve((size_t)3538944 * 2);
    _Float16* ff1h   = (_Float16*)carve((size_t)14155776 * 2);
    _Float16* ff2h   = (_Float16*)carve((size_t)14155776 * 2);
    _Float16* relh   = (_Float16*)carve((size_t)(926208 + 8192) * 2); // +pad for N=256 staging
    _Float16* cw11   = (_Float16*)carve((size_t)294912 * 2);
    _Float16* cw12   = (_Float16*)carve((size_t)1769472 * 2);
    _Float16* cw1r   = (_Float16*)carve((size_t)98304 * 2);
    _Float16* cw21   = (_Float16*)carve((size_t)1769472 * 2);
    _Float16* cw22   = (_Float16*)carve((size_t)1769472 * 2);
    _Float16* cw2r   = (_Float16*)carve((size_t)589824 * 2);
    _Float16* xrawh  = (_Float16*)carve((size_t)3244032 * 2);
    float*    xseq_f = (float*)carve((size_t)4915200 * 4);
    _Float16* xseq_h = (_Float16*)carve((size_t)4915200 * 2);
    _Float16* qkvb   = (_Float16*)carve((size_t)14745600 * 2);
    _Float16* ohb    = (_Float16*)carve((size_t)4915200 * 2);
    float*    af     = (float*)carve((size_t)4915200 * 4);
    char*     hhreg  = carve((size_t)19660800 * 2);
    float*    yf     = (float*)carve((size_t)4915200 * 4);
    // phase-overlapped aliases (all strictly sequential producer->consumer):
    _Float16* h1_rb1 = qkvb;
    float*    r_rb1  = (float*)hhreg;
    _Float16* out1   = (_Float16*)af;
    _Float16* h1_rb2 = (_Float16*)xseq_f;
    float*    r_rb2  = yf;
    _Float16* out2   = ohb;
    float*    xlin   = (float*)hhreg;
    _Float16* posh   = (_Float16*)hhreg;
    _Float16* ffh    = (_Float16*)hhreg;

    dim3 blk(256, 1, 1);
    const float qscale = 0.10206207261596575f;
    auto grd = [](long n) { return dim3((unsigned)((n + 255) / 256), 1, 1); };
    #define GRID2(M, N) dim3((unsigned)((N) / 64), (unsigned)(((M) + 63) / 64), 1)

    // ---- weight conversion / packing ----
    f2h_k<<<grd(3244032), blk, 0, stream>>>(x_raw, xrawh, 3244032, 1.0f);
    f2h_k<<<grd(589824), blk, 0, stream>>>(w_in_w, w_in_h, 589824, 1.0f);
    f2h_k<<<grd(14155776), blk, 0, stream>>>(ff1w, ff1h, 14155776, 1.0f);
    f2h_k<<<grd(14155776), blk, 0, stream>>>(ff2w, ff2h, 14155776, 1.0f);
    f2h_k<<<grd(926208), blk, 0, stream>>>(rel, relh, 926208, qscale); // fold q-scale
    pack_qkv_k<<<grd((long)NL * 2304 * DM), blk, 0, stream>>>(wq, wk, wv, qkvw);
    pack_wo_k<<<grd((long)NL * DM * DM), blk, 0, stream>>>(wo, wow);
    pack_conv_k<<<grd(294912), blk, 0, stream>>>(rb1_c1w, cw11, DM, FIN, 3);
    pack_conv_k<<<grd(1769472), blk, 0, stream>>>(rb1_c2w, cw12, DM, DM, 3);
    pack_conv_k<<<grd(98304), blk, 0, stream>>>(rb1_crw, cw1r, DM, FIN, 1);
    pack_conv_k<<<grd(1769472), blk, 0, stream>>>(rb2_c1w, cw21, DM, DM, 3);
    pack_conv_k<<<grd(1769472), blk, 0, stream>>>(rb2_c2w, cw22, DM, DM, 3);
    pack_conv_k<<<grd(589824), blk, 0, stream>>>(rb2_crw, cw2r, DM, DM, 1);

    // ---- resblock 1 (T 396 -> 198) ----
    gemm_k<true, EPI_CONV_F32><<<GRID2(M1, DM), blk, 0, stream>>>(
        xrawh, cw1r, r_rb1, nullptr, rb1_crb, rb1_sr, rb1_br, nullptr,
        M1, DM, FIN, FIN, T1, T0, 2, 1, 0, 0, 0);
    gemm_k<true, EPI_CONV_RELU_H><<<GRID2(M1, DM), blk, 0, stream>>>(
        xrawh, cw11, nullptr, h1_rb1, rb1_c1b, rb1_s1, rb1_b1, nullptr,
        M1, DM, FIN, FIN, T1, T0, 2, 3, 0, 0, 0);
    gemm_k<true, EPI_CONV_ADD_RELU_H><<<GRID2(M1, DM), blk, 0, stream>>>(
        h1_rb1, cw12, nullptr, out1, rb1_c2b, rb1_s2, rb1_b2, r_rb1,
        M1, DM, DM, DM, T1, T1, 1, 3, 0, 0, 0);

    // ---- resblock 2 (T 198 -> 99) ----
    gemm_k<true, EPI_CONV_F32><<<GRID2(M2, DM), blk, 0, stream>>>(
        out1, cw2r, r_rb2, nullptr, rb2_crb, rb2_sr, rb2_br, nullptr,
        M2, DM, DM, DM, T2, T1, 2, 1, 0, 0, 0);
    gemm_k<true, EPI_CONV_RELU_H><<<GRID2(M2, DM), blk, 0, stream>>>(
        out1, cw21, nullptr, h1_rb2, rb2_c1b, rb2_s1, rb2_b1, nullptr,
        M2, DM, DM, DM, T2, T1, 2, 3, 0, 0, 0);
    gemm_k<true, EPI_CONV_ADD_RELU_H><<<GRID2(M2, DM), blk, 0, stream>>>(
        h1_rb2, cw22, nullptr, out2, rb2_c2b, rb2_s2, rb2_b2, r_rb2,
        M2, DM, DM, DM, T2, T2, 1, 3, 0, 0, 0);

    // ---- input projection + cls concat ----
    gemm_k<false, EPI_F32><<<GRID2(M2, DM), blk, 0, stream>>>(
        out2, w_in_h, xlin, nullptr, w_in_b, nullptr, nullptr, nullptr,
        M2, DM, DM, DM, 0, 0, 0, 0, 0, 0, 0);
    concat_k<<<grd((long)MSEQ * DM), blk, 0, stream>>>(xlin, cls, xseq_f, xseq_h);

    // ---- transformer layers ----
    for (int l = 0; l < NL; ++l) {
        gemm_k<false, EPI_H><<<GRID2(MSEQ, 2304), blk, 0, stream>>>(
            xseq_h, qkvw + (size_t)l * 2304 * DM, nullptr, qkvb,
            nullptr, nullptr, nullptr, nullptr,
            MSEQ, 2304, DM, DM, 0, 0, 0, 0, 0, 0, 0);
        // pos[h] = q_h (6400x96) @ rel_h^T (256x96, 199 valid) -- batched over heads
        gemm_k<false, EPI_H><<<dim3(POSN / 64, MSEQ / 64, NHEAD), blk, 0, stream>>>(
            qkvb, relh + (size_t)l * NHEAD * NREL * DQ, nullptr, posh,
            nullptr, nullptr, nullptr, nullptr,
            MSEQ, POSN, DQ, 2304, 0, 0, 0, 0,
            (size_t)DQ, (size_t)NREL * DQ, (size_t)MSEQ * POSN);
        attn_k<<<dim3(NHEAD, B_, 1), blk, 0, stream>>>(qkvb, posh, ohb);
        gemm_k<false, EPI_F32><<<GRID2(MSEQ, DM), blk, 0, stream>>>(
            ohb, wow + (size_t)l * DM * DM, af, nullptr,
            nullptr, nullptr, nullptr, nullptr,
            MSEQ, DM, DM, DM, 0, 0, 0, 0, 0, 0, 0);
        ln_k<<<dim3(MSEQ), blk, 0, stream>>>(xseq_f, af, ln1g + l * DM, ln1b + l * DM,
                                             xseq_f, xseq_h);
        gemm_k<false, EPI_RELU_H><<<GRID2(MSEQ, DFF), blk, 0, stream>>>(
            xseq_h, ff1h + (size_t)l * DFF * DM, nullptr, ffh,
            ff1b + l * DFF, nullptr, nullptr, nullptr,
            MSEQ, DFF, DM, DM, 0, 0, 0, 0, 0, 0, 0);
        gemm_k<false, EPI_F32><<<GRID2(MSEQ, DM), blk, 0, stream>>>(
            ffh, ff2h + (size_t)l * DM * DFF, yf, nullptr,
            ff2b + l * DM, nullptr, nullptr, nullptr,
            MSEQ, DM, DFF, DFF, 0, 0, 0, 0, 0, 0, 0);
        ln_k<<<dim3(MSEQ), blk, 0, stream>>>(xseq_f, yf, ln2g + l * DM, ln2b + l * DM,
                                             xseq_f, xseq_h);
    }

    // ---- classifier head ----
    out_k<<<dim3(B_), blk, 0, stream>>>(xseq_f, w_out_w, w_out_b, (float*)d_out);
    #undef GRID2
}

// Round 2
// 2467.734 us; speedup vs baseline: 1.7548x; 1.7548x over previous
//
#include <hip/hip_runtime.h>

typedef _Float16 h8 __attribute__((ext_vector_type(8)));
typedef float f4 __attribute__((ext_vector_type(4)));

namespace {

constexpr int DM   = 768;
constexpr int NHEAD= 8;
constexpr int DQ   = 96;
constexpr int DFF  = 3072;
constexpr int NL   = 6;
constexpr int B_   = 64;
constexpr int T0   = 396, T1 = 198, T2 = 99;
constexpr int FIN  = 128;
constexpr int L_   = 100;
constexpr int MSEQ = B_ * L_;    // 6400
constexpr int M1   = B_ * T1;    // 12672
constexpr int M2   = B_ * T2;    // 6336
constexpr int NREL = 201;
constexpr int POSN = 256;        // padded 199 -> 256

enum { EPI_F32 = 0, EPI_RELU_H, EPI_H, EPI_CONV_F32, EPI_CONV_RELU_H, EPI_CONV_ADD_RELU_H };

// ---------------------------------------------------------------------------
// Generic MFMA GEMM:  C[M,N] = A[M,K] @ B[N,K]^T   (B stored row-major (N,K))
// ---------------------------------------------------------------------------
template<bool CONV, int EPI>
__global__ __launch_bounds__(256)
void gemm_k(const _Float16* __restrict__ A, const _Float16* __restrict__ B,
            float* __restrict__ Cf, _Float16* __restrict__ Ch,
            const float* __restrict__ bias, const float* __restrict__ bns,
            const float* __restrict__ bnb, const float* __restrict__ res,
            int M, int N, int K, int lda,
            int T_out, int T_in, int stride_t, int KS,
            size_t a_z, size_t b_z, size_t c_z)
{
    __shared__ _Float16 As[64][40];   // pitch 40 halves (80B) -> conflict-light
    __shared__ _Float16 Bs[64][40];

    A += (size_t)blockIdx.z * a_z;
    B += (size_t)blockIdx.z * b_z;

    const int tid  = threadIdx.x;
    const int lane = tid & 63;
    const int wid  = tid >> 6;
    const int m0   = blockIdx.y * 64;
    const int n0   = blockIdx.x * 64;
    const int wm   = (wid >> 1) * 32;
    const int wn   = (wid & 1) * 32;

    f4 acc[2][2];
    #pragma unroll
    for (int i = 0; i < 2; ++i)
        #pragma unroll
        for (int j = 0; j < 2; ++j)
            #pragma unroll
            for (int q = 0; q < 4; ++q) acc[i][j][q] = 0.0f;

    const int srow = tid >> 2;        // 0..63 staging row
    const int skq  = (tid & 3) * 8;   // 0,8,16,24

    const bool mrow_ok = (m0 + srow) < M;
    int ab = 0, at = 0;
    if (CONV) { int m = m0 + srow; ab = m / T_out; at = m - ab * T_out; }

    const int nks = CONV ? KS : 1;
    const int pad = CONV ? ((KS - 1) >> 1) : 0;

    for (int dk = 0; dk < nks; ++dk) {
        const _Float16* Bd = B + (size_t)dk * ((size_t)N * (size_t)K);
        const _Float16* Arow = nullptr;
        bool aok;
        if (CONV) {
            int tin = at * stride_t + dk - pad;
            aok = mrow_ok && tin >= 0 && tin < T_in;
            if (aok) Arow = A + ((size_t)ab * T_in + tin) * (size_t)lda;
        } else {
            aok = mrow_ok;
            if (aok) Arow = A + (size_t)(m0 + srow) * (size_t)lda;
        }
        const _Float16* Brow = Bd + (size_t)(n0 + srow) * (size_t)K;

        for (int k0 = 0; k0 < K; k0 += 32) {
            h8 av;
            #pragma unroll
            for (int q = 0; q < 8; ++q) av[q] = (_Float16)0.0f;
            if (aok) av = *(const h8*)(Arow + k0 + skq);
            h8 bv = *(const h8*)(Brow + k0 + skq);
            *(h8*)&As[srow][skq] = av;
            *(h8*)&Bs[srow][skq] = bv;
            __syncthreads();

            const int fr = lane & 15;
            const int fk = (lane >> 4) * 8;
            h8 a0 = *(const h8*)&As[wm + fr][fk];
            h8 a1 = *(const h8*)&As[wm + 16 + fr][fk];
            h8 b0 = *(const h8*)&Bs[wn + fr][fk];
            h8 b1 = *(const h8*)&Bs[wn + 16 + fr][fk];
            acc[0][0] = __builtin_amdgcn_mfma_f32_16x16x32_f16(a0, b0, acc[0][0], 0, 0, 0);
            acc[0][1] = __builtin_amdgcn_mfma_f32_16x16x32_f16(a0, b1, acc[0][1], 0, 0, 0);
            acc[1][0] = __builtin_amdgcn_mfma_f32_16x16x32_f16(a1, b0, acc[1][0], 0, 0, 0);
            acc[1][1] = __builtin_amdgcn_mfma_f32_16x16x32_f16(a1, b1, acc[1][1], 0, 0, 0);
            __syncthreads();
        }
    }

    // Epilogue. Verified C/D mapping: col = lane&15, row = (lane>>4)*4 + reg.
    const int fr  = lane & 15;
    const int fq4 = (lane >> 4) * 4;
    float*     Cfo = Cf ? Cf + (size_t)blockIdx.z * c_z : nullptr;
    _Float16*  Cho = Ch ? Ch + (size_t)blockIdx.z * c_z : nullptr;
    #pragma unroll
    for (int mi = 0; mi < 2; ++mi)
        #pragma unroll
        for (int ni = 0; ni < 2; ++ni)
            #pragma unroll
            for (int r = 0; r < 4; ++r) {
                int row = m0 + wm + mi * 16 + fq4 + r;
                int col = n0 + wn + ni * 16 + fr;
                if (row >= M) continue;
                float v = acc[mi][ni][r];
                size_t off = (size_t)row * N + col;
                if (EPI == EPI_F32) {
                    if (bias) v += bias[col];
                    Cfo[off] = v;
                } else if (EPI == EPI_RELU_H) {
                    if (bias) v += bias[col];
                    Cho[off] = (_Float16)fmaxf(v, 0.0f);
                } else if (EPI == EPI_H) {
                    Cho[off] = (_Float16)v;
                } else if (EPI == EPI_CONV_F32) {
                    v = bns[col] * (v + bias[col]) + bnb[col];
                    Cfo[off] = v;
                } else if (EPI == EPI_CONV_RELU_H) {
                    v = bns[col] * (v + bias[col]) + bnb[col];
                    Cho[off] = (_Float16)fmaxf(v, 0.0f);
                } else { // EPI_CONV_ADD_RELU_H
                    v = bns[col] * (v + bias[col]) + bnb[col] + res[off];
                    Cho[off] = (_Float16)fmaxf(v, 0.0f);
                }
            }
}

// ------------------------- small helper kernels ----------------------------

__global__ void f2h_k(const float* __restrict__ in, _Float16* __restrict__ out,
                      long n, float scale)
{
    long i = (long)blockIdx.x * blockDim.x + threadIdx.x;
    if (i < n) out[i] = (_Float16)(in[i] * scale);
}

__global__ void pack_qkv_k(const float* __restrict__ wq, const float* __restrict__ wk,
                           const float* __restrict__ wv, _Float16* __restrict__ out)
{
    long i = (long)blockIdx.x * blockDim.x + threadIdx.x;
    if (i >= (long)NL * 2304 * DM) return;
    int  f = (int)(i % DM);
    long r = i / DM;
    int  n = (int)(r % 2304);
    int  l = (int)(r / 2304);
    int  s = n / DM, hn = n % DM, h = hn / DQ, a = hn % DQ;
    const float* src = (s == 0) ? wq : ((s == 1) ? wk : wv);
    out[i] = (_Float16)src[(((long)l * NHEAD + h) * DM + f) * DQ + a];
}

__global__ void pack_wo_k(const float* __restrict__ wo, _Float16* __restrict__ out)
{
    long i = (long)blockIdx.x * blockDim.x + threadIdx.x;
    if (i >= (long)NL * DM * DM) return;
    int  ha = (int)(i % DM);
    long r  = i / DM;
    int  f  = (int)(r % DM);
    int  l  = (int)(r / DM);
    int  h = ha / DQ, a = ha % DQ;
    out[i] = (_Float16)wo[(((long)l * NHEAD + h) * DQ + a) * DM + f];
}

__global__ void pack_conv_k(const float* __restrict__ w, _Float16* __restrict__ out,
                            int Cout, int Cin, int KS)
{
    long i = (long)blockIdx.x * blockDim.x + threadIdx.x;
    if (i >= (long)Cout * Cin * KS) return;
    int  ci = (int)(i % Cin);
    long r  = i / Cin;
    int  co = (int)(r % Cout);
    int  dk = (int)(r / Cout);
    out[i] = (_Float16)w[((long)co * Cin + ci) * KS + dk];
}

__global__ void concat_k(const float* __restrict__ xlin, const float* __restrict__ cls,
                         float* __restrict__ xf, _Float16* __restrict__ xh)
{
    long i = (long)blockIdx.x * blockDim.x + threadIdx.x;
    if (i >= (long)MSEQ * DM) return;
    int  c = (int)(i % DM);
    long m = i / DM;
    int  b = (int)(m / L_), t = (int)(m % L_);
    float v = (t == 0) ? cls[c] : xlin[((long)b * (L_ - 1) + (t - 1)) * DM + c];
    xf[i] = v;
    xh[i] = (_Float16)v;
}

__global__ __launch_bounds__(256)
void ln_k(const float* x, const float* __restrict__ d,
          const float* __restrict__ g, const float* __restrict__ bb,
          float* xo, _Float16* __restrict__ xh)
{
    long row = blockIdx.x;
    const float* xr = x + row * DM;
    const float* dr = d + row * DM;
    float v[3];
    float s = 0.0f;
    #pragma unroll
    for (int k = 0; k < 3; ++k) {
        int c = threadIdx.x + 256 * k;
        v[k] = xr[c] + dr[c];
        s += v[k];
    }
    __shared__ float red[8];
    #pragma unroll
    for (int o = 32; o; o >>= 1) s += __shfl_xor(s, o, 64);
    int w = threadIdx.x >> 6, lane = threadIdx.x & 63;
    if (lane == 0) red[w] = s;
    __syncthreads();
    s = red[0] + red[1] + red[2] + red[3];
    float mean = s * (1.0f / DM);
    float vs = 0.0f;
    #pragma unroll
    for (int k = 0; k < 3; ++k) { float t = v[k] - mean; vs += t * t; }
    #pragma unroll
    for (int o = 32; o; o >>= 1) vs += __shfl_xor(vs, o, 64);
    if (lane == 0) red[4 + w] = vs;
    __syncthreads();
    vs = red[4] + red[5] + red[6] + red[7];
    float rstd = rsqrtf(vs * (1.0f / DM) + 1e-5f);
    #pragma unroll
    for (int k = 0; k < 3; ++k) {
        int c = threadIdx.x + 256 * k;
        float y = (v[k] - mean) * rstd * g[c] + bb[c];
        xo[row * DM + c] = y;
        xh[row * DM + c] = (_Float16)y;
    }
}

// ---------------------------------------------------------------------------
// MFMA fused attention. One block per (h = blockIdx.x, b = blockIdx.y),
// 4 waves. L=100 padded to 128. S = Q@K^T (Q frags direct from global/L2,
// K staged LDS), register softmax via C-layout row groups, P->LDS (f16,
// overlays K region), O = P@V^T (V transposed into LDS at stage time).
// LDS: P region 34816B (K's 26624B overlays it) + Vt 26112B = 60928B.
// ---------------------------------------------------------------------------
constexpr int LP = 128;    // padded L
constexpr int KP = 104;    // K LDS pitch (halves); 208B rows, 16B aligned
constexpr int PP = 136;    // P / Vt LDS pitch (halves); 272B rows

__global__ __launch_bounds__(256)
void attn_k(const _Float16* __restrict__ qkv, const _Float16* __restrict__ pos,
            _Float16* __restrict__ o)
{
    __shared__ __align__(16) char smem[60928];
    _Float16* Ks = (_Float16*)smem;            // [128][104] (phase 1)
    _Float16* Ps = (_Float16*)smem;            // [128][136] (phase 2, overlays Ks)
    _Float16* Vt = (_Float16*)(smem + 34816);  // [96][136]

    const int h = blockIdx.x, b = blockIdx.y;
    const int tid = threadIdx.x, lane = tid & 63, w = tid >> 6;
    const _Float16* base = qkv + (size_t)b * L_ * 2304 + h * DQ;
    const float qscale = 0.10206207261596575f;  // 96^-0.5

    // ---- stage K (zero-padded rows) + V^T ----
    {
        int row = tid >> 1;
        int c0  = (tid & 1) * 48;
        const bool real = row < L_;
        const _Float16* krow = base + 768 + (size_t)row * 2304;
        #pragma unroll
        for (int q = 0; q < 6; ++q) {
            int c = c0 + q * 8;
            h8 kv;
            #pragma unroll
            for (int e = 0; e < 8; ++e) kv[e] = (_Float16)0.0f;
            if (real) kv = *(const h8*)(krow + c);
            *(h8*)&Ks[row * KP + c] = kv;
        }
        for (int idx = tid; idx < DQ * LP; idx += 256) {
            int a = idx % DQ, j = idx / DQ;   // a-fast: coalesced global reads
            _Float16 v = (_Float16)0.0f;
            if (j < L_) v = base[1536 + (size_t)j * 2304 + a];
            Vt[a * PP + j] = v;
        }
    }
    __syncthreads();

    const int fr = lane & 15;          // fragment row/col index
    const int fk = (lane >> 4) * 8;    // fragment k offset
    const int rbase = w * 32 + ((lane >> 4) << 2);

    // ---- S = Q @ K^T : wave strip rows [w*32, w*32+32), 2x8 frags ----
    f4 acc[2][8];
    #pragma unroll
    for (int mi = 0; mi < 2; ++mi)
        #pragma unroll
        for (int ni = 0; ni < 8; ++ni)
            #pragma unroll
            for (int q = 0; q < 4; ++q) acc[mi][ni][q] = 0.0f;

    #pragma unroll
    for (int k0 = 0; k0 < DQ; k0 += 32) {
        // Q A-frags straight from global (L2-warm): row = strip + fr
        h8 a0 = *(const h8*)(base + (size_t)(w * 32 + fr) * 2304 + k0 + fk);
        h8 a1 = *(const h8*)(base + (size_t)(w * 32 + 16 + fr) * 2304 + k0 + fk);
        #pragma unroll
        for (int ni = 0; ni < 8; ++ni) {
            h8 bv = *(const h8*)&Ks[(ni * 16 + fr) * KP + k0 + fk];
            acc[0][ni] = __builtin_amdgcn_mfma_f32_16x16x32_f16(a0, bv, acc[0][ni], 0, 0, 0);
            acc[1][ni] = __builtin_amdgcn_mfma_f32_16x16x32_f16(a1, bv, acc[1][ni], 0, 0, 0);
        }
    }

    // ---- register softmax: row i lives in one 16-lane group x 8 frags ----
    const _Float16* posb = pos + ((size_t)h * MSEQ + (size_t)b * L_) * POSN;
    #pragma unroll
    for (int mi = 0; mi < 2; ++mi)
        #pragma unroll
        for (int r = 0; r < 4; ++r) {
            int i = rbase + mi * 16 + r;
            float s[8];
            #pragma unroll
            for (int ni = 0; ni < 8; ++ni) {
                int j = ni * 16 + fr;
                float v = -3.0e38f;
                if (i < L_ && j < L_)
                    v = acc[mi][ni][r] * qscale
                      + (float)posb[(size_t)i * POSN + (j - i + (L_ - 1))];
                s[ni] = v;
            }
            float m = s[0];
            #pragma unroll
            for (int ni = 1; ni < 8; ++ni) m = fmaxf(m, s[ni]);
            #pragma unroll
            for (int msk = 1; msk < 16; msk <<= 1) m = fmaxf(m, __shfl_xor(m, msk, 64));
            float sum = 0.0f;
            #pragma unroll
            for (int ni = 0; ni < 8; ++ni) { s[ni] = __expf(s[ni] - m); sum += s[ni]; }
            #pragma unroll
            for (int msk = 1; msk < 16; msk <<= 1) sum += __shfl_xor(sum, msk, 64);
            float inv = 1.0f / sum;
            #pragma unroll
            for (int ni = 0; ni < 8; ++ni) acc[mi][ni][r] = s[ni] * inv;
        }

    __syncthreads();   // all waves done reading Ks (P overlays it)

    #pragma unroll
    for (int mi = 0; mi < 2; ++mi)
        #pragma unroll
        for (int r = 0; r < 4; ++r) {
            int i = rbase + mi * 16 + r;
            #pragma unroll
            for (int ni = 0; ni < 8; ++ni)
                Ps[i * PP + ni * 16 + fr] = (_Float16)acc[mi][ni][r];
        }
    __syncthreads();

    // ---- O = P @ V^T : 2x6 frags, K=128 ----
    f4 acc2[2][6];
    #pragma unroll
    for (int mi = 0; mi < 2; ++mi)
        #pragma unroll
        for (int ni = 0; ni < 6; ++ni)
            #pragma unroll
            for (int q = 0; q < 4; ++q) acc2[mi][ni][q] = 0.0f;

    #pragma unroll
    for (int k0 = 0; k0 < LP; k0 += 32) {
        h8 a0 = *(const h8*)&Ps[(w * 32 + fr) * PP + k0 + fk];
        h8 a1 = *(const h8*)&Ps[(w * 32 + 16 + fr) * PP + k0 + fk];
        #pragma unroll
        for (int ni = 0; ni < 6; ++ni) {
            h8 bv = *(const h8*)&Vt[(ni * 16 + fr) * PP + k0 + fk];
            acc2[0][ni] = __builtin_amdgcn_mfma_f32_16x16x32_f16(a0, bv, acc2[0][ni], 0, 0, 0);
            acc2[1][ni] = __builtin_amdgcn_mfma_f32_16x16x32_f16(a1, bv, acc2[1][ni], 0, 0, 0);
        }
    }

    _Float16* ob = o + (size_t)b * L_ * DM + h * DQ;
    #pragma unroll
    for (int mi = 0; mi < 2; ++mi)
        #pragma unroll
        for (int r = 0; r < 4; ++r) {
            int i = rbase + mi * 16 + r;
            if (i < L_) {
                #pragma unroll
                for (int ni = 0; ni < 6; ++ni)
                    ob[(size_t)i * DM + ni * 16 + fr] = (_Float16)acc2[mi][ni][r];
            }
        }
}

// final: out[b, n] = x_seq[b, 0, :] . w_out[n, :] + bias[n]
__global__ __launch_bounds__(256)
void out_k(const float* __restrict__ xseq, const float* __restrict__ w,
           const float* __restrict__ bias, float* __restrict__ out)
{
    __shared__ float xs[DM];
    int b = blockIdx.x;
    for (int c = threadIdx.x; c < DM; c += 256) xs[c] = xseq[(size_t)b * L_ * DM + c];
    __syncthreads();
    int n = threadIdx.x;
    const f4* wr = (const f4*)(w + (size_t)n * DM);
    float acc = 0.0f;
    #pragma unroll 4
    for (int k4 = 0; k4 < DM / 4; ++k4) {
        f4 wv = wr[k4];
        f4 xv = *(const f4*)&xs[k4 * 4];
        acc += wv[0]*xv[0] + wv[1]*xv[1] + wv[2]*xv[2] + wv[3]*xv[3];
    }
    out[(size_t)b * 256 + n] = acc + bias[n];
}

} // anonymous namespace

// ---------------------------------------------------------------------------
extern "C" void kernel_launch(void* const* d_in, const int* in_sizes, int n_in,
                              void* d_out, int out_size, void* d_ws, size_t ws_size,
                              hipStream_t stream)
{
    (void)in_sizes; (void)n_in; (void)out_size; (void)ws_size;

    const float* x_raw   = (const float*)d_in[0];
    const float* rb1_c1w = (const float*)d_in[1];
    const float* rb1_c1b = (const float*)d_in[2];
    const float* rb1_s1  = (const float*)d_in[3];
    const float* rb1_b1  = (const float*)d_in[4];
    const float* rb1_c2w = (const float*)d_in[5];
    const float* rb1_c2b = (const float*)d_in[6];
    const float* rb1_s2  = (const float*)d_in[7];
    const float* rb1_b2  = (const float*)d_in[8];
    const float* rb1_crw = (const float*)d_in[9];
    const float* rb1_crb = (const float*)d_in[10];
    const float* rb1_sr  = (const float*)d_in[11];
    const float* rb1_br  = (const float*)d_in[12];
    const float* rb2_c1w = (const float*)d_in[13];
    const float* rb2_c1b = (const float*)d_in[14];
    const float* rb2_s1  = (const float*)d_in[15];
    const float* rb2_b1  = (const float*)d_in[16];
    const float* rb2_c2w = (const float*)d_in[17];
    const float* rb2_c2b = (const float*)d_in[18];
    const float* rb2_s2  = (const float*)d_in[19];
    const float* rb2_b2  = (const float*)d_in[20];
    const float* rb2_crw = (const float*)d_in[21];
    const float* rb2_crb = (const float*)d_in[22];
    const float* rb2_sr  = (const float*)d_in[23];
    const float* rb2_br  = (const float*)d_in[24];
    const float* w_in_w  = (const float*)d_in[25];
    const float* w_in_b  = (const float*)d_in[26];
    const float* cls     = (const float*)d_in[27];
    const float* wq      = (const float*)d_in[28];
    const float* wk      = (const float*)d_in[29];
    const float* wv      = (const float*)d_in[30];
    const float* wo      = (const float*)d_in[31];
    const float* rel     = (const float*)d_in[32];
    const float* ln1g    = (const float*)d_in[33];
    const float* ln1b    = (const float*)d_in[34];
    const float* ln2g    = (const float*)d_in[35];
    const float* ln2b    = (const float*)d_in[36];
    const float* ff1w    = (const float*)d_in[37];
    const float* ff1b    = (const float*)d_in[38];
    const float* ff2w    = (const float*)d_in[39];
    const float* ff2b    = (const float*)d_in[40];
    const float* w_out_w = (const float*)d_in[41];
    const float* w_out_b = (const float*)d_in[42];

    char* base = (char*)d_ws;
    size_t off = 0;
    auto carve = [&](size_t bytes) -> char* {
        char* p = base + off;
        off = (off + bytes + 255) & ~(size_t)255;
        return p;
    };
    _Float16* w_in_h = (_Float16*)carve((size_t)589824 * 2);
    _Float16* qkvw   = (_Float16*)carve((size_t)10616832 * 2);
    _Float16* wow    = (_Float16*)carve((size_t)3538944 * 2);
    _Float16* ff1h   = (_Float16*)carve((size_t)14155776 * 2);
    _Float16* ff2h   = (_Float16*)carve((size_t)14155776 * 2);
    _Float16* relh   = (_Float16*)carve((size_t)(926208 + 8192) * 2);
    _Float16* cw11   = (_Float16*)carve((size_t)294912 * 2);
    _Float16* cw12   = (_Float16*)carve((size_t)1769472 * 2);
    _Float16* cw1r   = (_Float16*)carve((size_t)98304 * 2);
    _Float16* cw21   = (_Float16*)carve((size_t)1769472 * 2);
    _Float16* cw22   = (_Float16*)carve((size_t)1769472 * 2);
    _Float16* cw2r   = (_Float16*)carve((size_t)589824 * 2);
    _Float16* xrawh  = (_Float16*)carve((size_t)3244032 * 2);
    float*    xseq_f = (float*)carve((size_t)4915200 * 4);
    _Float16* xseq_h = (_Float16*)carve((size_t)4915200 * 2);
    _Float16* qkvb   = (_Float16*)carve((size_t)14745600 * 2);
    _Float16* ohb    = (_Float16*)carve((size_t)4915200 * 2);
    float*    af     = (float*)carve((size_t)4915200 * 4);
    char*     hhreg  = carve((size_t)19660800 * 2);
    float*    yf     = (float*)carve((size_t)4915200 * 4);
    _Float16* h1_rb1 = qkvb;
    float*    r_rb1  = (float*)hhreg;
    _Float16* out1   = (_Float16*)af;
    _Float16* h1_rb2 = (_Float16*)xseq_f;
    float*    r_rb2  = yf;
    _Float16* out2   = ohb;
    float*    xlin   = (float*)hhreg;
    _Float16* posh   = (_Float16*)hhreg;
    _Float16* ffh    = (_Float16*)hhreg;

    dim3 blk(256, 1, 1);
    const float qscale = 0.10206207261596575f;
    auto grd = [](long n) { return dim3((unsigned)((n + 255) / 256), 1, 1); };
    #define GRID2(M, N) dim3((unsigned)((N) / 64), (unsigned)(((M) + 63) / 64), 1)

    f2h_k<<<grd(3244032), blk, 0, stream>>>(x_raw, xrawh, 3244032, 1.0f);
    f2h_k<<<grd(589824), blk, 0, stream>>>(w_in_w, w_in_h, 589824, 1.0f);
    f2h_k<<<grd(14155776), blk, 0, stream>>>(ff1w, ff1h, 14155776, 1.0f);
    f2h_k<<<grd(14155776), blk, 0, stream>>>(ff2w, ff2h, 14155776, 1.0f);
    f2h_k<<<grd(926208), blk, 0, stream>>>(rel, relh, 926208, qscale);
    pack_qkv_k<<<grd((long)NL * 2304 * DM), blk, 0, stream>>>(wq, wk, wv, qkvw);
    pack_wo_k<<<grd((long)NL * DM * DM), blk, 0, stream>>>(wo, wow);
    pack_conv_k<<<grd(294912), blk, 0, stream>>>(rb1_c1w, cw11, DM, FIN, 3);
    pack_conv_k<<<grd(1769472), blk, 0, stream>>>(rb1_c2w, cw12, DM, DM, 3);
    pack_conv_k<<<grd(98304), blk, 0, stream>>>(rb1_crw, cw1r, DM, FIN, 1);
    pack_conv_k<<<grd(1769472), blk, 0, stream>>>(rb2_c1w, cw21, DM, DM, 3);
    pack_conv_k<<<grd(1769472), blk, 0, stream>>>(rb2_c2w, cw22, DM, DM, 3);
    pack_conv_k<<<grd(589824), blk, 0, stream>>>(rb2_crw, cw2r, DM, DM, 1);

    gemm_k<true, EPI_CONV_F32><<<GRID2(M1, DM), blk, 0, stream>>>(
        xrawh, cw1r, r_rb1, nullptr, rb1_crb, rb1_sr, rb1_br, nullptr,
        M1, DM, FIN, FIN, T1, T0, 2, 1, 0, 0, 0);
    gemm_k<true, EPI_CONV_RELU_H><<<GRID2(M1, DM), blk, 0, stream>>>(
        xrawh, cw11, nullptr, h1_rb1, rb1_c1b, rb1_s1, rb1_b1, nullptr,
        M1, DM, FIN, FIN, T1, T0, 2, 3, 0, 0, 0);
    gemm_k<true, EPI_CONV_ADD_RELU_H><<<GRID2(M1, DM), blk, 0, stream>>>(
        h1_rb1, cw12, nullptr, out1, rb1_c2b, rb1_s2, rb1_b2, r_rb1,
        M1, DM, DM, DM, T1, T1, 1, 3, 0, 0, 0);

    gemm_k<true, EPI_CONV_F32><<<GRID2(M2, DM), blk, 0, stream>>>(
        out1, cw2r, r_rb2, nullptr, rb2_crb, rb2_sr, rb2_br, nullptr,
        M2, DM, DM, DM, T2, T1, 2, 1, 0, 0, 0);
    gemm_k<true, EPI_CONV_RELU_H><<<GRID2(M2, DM), blk, 0, stream>>>(
        out1, cw21, nullptr, h1_rb2, rb2_c1b, rb2_s1, rb2_b1, nullptr,
        M2, DM, DM, DM, T2, T1, 2, 3, 0, 0, 0);
    gemm_k<true, EPI_CONV_ADD_RELU_H><<<GRID2(M2, DM), blk, 0, stream>>>(
        h1_rb2, cw22, nullptr, out2, rb2_c2b, rb2_s2, rb2_b2, r_rb2,
        M2, DM, DM, DM, T2, T2, 1, 3, 0, 0, 0);

    gemm_k<false, EPI_F32><<<GRID2(M2, DM), blk, 0, stream>>>(
        out2, w_in_h, xlin, nullptr, w_in_b, nullptr, nullptr, nullptr,
        M2, DM, DM, DM, 0, 0, 0, 0, 0, 0, 0);
    concat_k<<<grd((long)MSEQ * DM), blk, 0, stream>>>(xlin, cls, xseq_f, xseq_h);

    for (int l = 0; l < NL; ++l) {
        gemm_k<false, EPI_H><<<GRID2(MSEQ, 2304), blk, 0, stream>>>(
            xseq_h, qkvw + (size_t)l * 2304 * DM, nullptr, qkvb,
            nullptr, nullptr, nullptr, nullptr,
            MSEQ, 2304, DM, DM, 0, 0, 0, 0, 0, 0, 0);
        gemm_k<false, EPI_H><<<dim3(POSN / 64, MSEQ / 64, NHEAD), blk, 0, stream>>>(
            qkvb, relh + (size_t)l * NHEAD * NREL * DQ, nullptr, posh,
            nullptr, nullptr, nullptr, nullptr,
            MSEQ, POSN, DQ, 2304, 0, 0, 0, 0,
            (size_t)DQ, (size_t)NREL * DQ, (size_t)MSEQ * POSN);
        attn_k<<<dim3(NHEAD, B_, 1), blk, 0, stream>>>(qkvb, posh, ohb);
        gemm_k<false, EPI_F32><<<GRID2(MSEQ, DM), blk, 0, stream>>>(
            ohb, wow + (size_t)l * DM * DM, af, nullptr,
            nullptr, nullptr, nullptr, nullptr,
            MSEQ, DM, DM, DM, 0, 0, 0, 0, 0, 0, 0);
        ln_k<<<dim3(MSEQ), blk, 0, stream>>>(xseq_f, af, ln1g + l * DM, ln1b + l * DM,
                                             xseq_f, xseq_h);
        gemm_k<false, EPI_RELU_H><<<GRID2(MSEQ, DFF), blk, 0, stream>>>(
            xseq_h, ff1h + (size_t)l * DFF * DM, nullptr, ffh,
            ff1b + l * DFF, nullptr, nullptr, nullptr,
            MSEQ, DFF, DM, DM, 0, 0, 0, 0, 0, 0, 0);
        gemm_k<false, EPI_F32><<<GRID2(MSEQ, DM), blk, 0, stream>>>(
            ffh, ff2h + (size_t)l * DM * DFF, yf, nullptr,
            ff2b + l * DM, nullptr, nullptr, nullptr,
            MSEQ, DM, DFF, DFF, 0, 0, 0, 0, 0, 0, 0);
        ln_k<<<dim3(MSEQ), blk, 0, stream>>>(xseq_f, yf, ln2g + l * DM, ln2b + l * DM,
                                             xseq_f, xseq_h);
    }

    out_k<<<dim3(B_), blk, 0, stream>>>(xseq_f, w_out_w, w_out_b, (float*)d_out);
    #undef GRID2
}